// Round 3
// baseline (933.208 us; speedup 1.0000x reference)
//
#include <hip/hip_runtime.h>
#include <hip/hip_bf16.h>
#include <cstdint>
#include <cstddef>

typedef unsigned short u16;
typedef __attribute__((ext_vector_type(8))) __bf16 bf16x8;
typedef __attribute__((ext_vector_type(4))) float f32x4;

#define EPS_BN 1e-5f

__device__ __forceinline__ u16 f2bf(float f) {
    union { float f; uint32_t u; } v; v.f = f;
    uint32_t u = v.u;
    u += 0x7FFFu + ((u >> 16) & 1u);   // round-to-nearest-even
    return (u16)(u >> 16);
}
__device__ __forceinline__ float bf2f(u16 s) {
    union { uint32_t u; float f; } v; v.u = ((uint32_t)s) << 16;
    return v.f;
}

union Pack8 { u16 u[8]; uint4 v4; };
union Pack4 { u16 u[4]; uint2 v2; };

// async global -> LDS, 16B per lane; LDS dest = wave-uniform base + lane*16
typedef __attribute__((address_space(1))) const unsigned char as1c;
typedef __attribute__((address_space(3))) unsigned char as3;
__device__ __forceinline__ void gld_lds16(const void* g, void* l) {
    __builtin_amdgcn_global_load_lds((as1c*)g, (as3*)l, 16, 0, 0);
}

// ---------------------------------------------------------------------------
// Transpose NCHW fp32 -> NHWC bf16 (search + kernel inputs in one launch)
// ---------------------------------------------------------------------------
__device__ __forceinline__ void tr_one(const float* __restrict__ in,
                                       u16* __restrict__ out, int P, int p)
{
    int b = p / P, pp = p - b * P;
    const float* ip = in + (size_t)b * 256 * P + pp;
    u16* op = out + (size_t)p * 256;
    #pragma unroll 4
    for (int cg = 0; cg < 32; cg++) {
        Pack8 pk;
        #pragma unroll
        for (int i = 0; i < 8; i++)
            pk.u[i] = f2bf(ip[(size_t)(cg * 8 + i) * P]);
        *(uint4*)(op + cg * 8) = pk.v4;
    }
}

__global__ __launch_bounds__(256)
void tr_all(const float* __restrict__ s, const float* __restrict__ k,
            u16* __restrict__ so, u16* __restrict__ ko)
{
    int blk = blockIdx.x;
    if (blk < 481) {
        int p = blk * 256 + threadIdx.x;
        if (p < 128 * 961) tr_one(s, so, 961, p);
    } else {
        int p = (blk - 481) * 256 + threadIdx.x;
        if (p < 128 * 49) tr_one(k, ko, 49, p);
    }
}

// ---------------------------------------------------------------------------
// Implicit-im2col GEMM, NHWC bf16 input:
//   out[oc, (b,oy,ox)] = sum_k W[oc,k] * X[(b,oy,ox), k],  k = (tap, c)
// 128x128 tile, BK=64, 4 waves, 4x4 frags of 16x16x32 bf16 MFMA.
// Staging via global_load_lds width=16. LDS k-slab layout:
//   slab kc (8 ch = 16B) x 128 rows x 16B; addr(kc,row) = kc*1024 + row*8 (u16)
// waves 0,1 stage A (row = tid 0..127); waves 2,3 stage B (pixel = tid-128).
// ---------------------------------------------------------------------------
template<int TAPS, bool NHWC_OUT, typename OutT, bool RELU>
__global__ __launch_bounds__(256)
void conv_gemm(const u16* __restrict__ in, const u16* __restrict__ W,
               const float* __restrict__ scale, const float* __restrict__ shift,
               OutT* __restrict__ out, int Hi, int Wi, int Ho, int Wo)
{
    constexpr int KT = TAPS * 256;
    constexpr int KB = KT / 64;
    const int HoWo = Ho * Wo;

    __shared__ u16 Alds[8192];   // 16 KB
    __shared__ u16 Blds[8192];   // 16 KB

    const int tid = threadIdx.x;
    const int it = blockIdx.x;   // I tile (oc): 0..1
    const int jt = blockIdx.y;   // J tile
    const int wv = tid >> 6;
    const int lane = tid & 63;
    const int h = wv & 1;        // which 64-row half this wave stages

    // ---- A staging base (waves 0,1): weight row = tid (0..127)
    const u16* gA = W + (size_t)(it * 128 + (tid & 127)) * KT;
    // ---- B staging base (waves 2,3): pixel = tid & 127
    {
    }
    const int p = tid & 127;
    const int jg = jt * 128 + p;
    const int bb = jg / HoWo;
    const int msp = jg - bb * HoWo;
    const int oy = msp / Wo;
    const int ox = msp - oy * Wo;
    const u16* gB = in + ((size_t)(bb * Hi + oy) * Wi + ox) * 256;

    // ---- MFMA coords
    const int wi = (wv >> 1) * 64;
    const int wj = (wv & 1) * 64;
    const int lr = lane & 15;
    const int lq = lane >> 4;

    f32x4 acc[4][4];
    #pragma unroll
    for (int a = 0; a < 4; a++)
        #pragma unroll
        for (int b = 0; b < 4; b++)
            acc[a][b] = (f32x4){0.f, 0.f, 0.f, 0.f};

    for (int kb = 0; kb < KB; kb++) {
        const int tap = (TAPS == 1) ? 0 : (kb >> 2);
        const int c0  = (TAPS == 1) ? (kb * 64) : ((kb & 3) * 64);
        __syncthreads();
        if (wv < 2) {
            const u16* g = gA + tap * 256 + c0;
            #pragma unroll
            for (int kc = 0; kc < 8; kc++)
                gld_lds16(g + kc * 8, &Alds[kc * 1024 + h * 512]);
        } else {
            int ky = 0, kx = 0;
            if (TAPS == 9) { ky = tap / 3; kx = tap - ky * 3; }
            const u16* g = gB + (size_t)(ky * Wi + kx) * 256 + c0;
            #pragma unroll
            for (int kc = 0; kc < 8; kc++)
                gld_lds16(g + kc * 8, &Blds[kc * 1024 + h * 512]);
        }
        __syncthreads();
        // ---- MFMA: 2 k-steps of 32
        #pragma unroll
        for (int ks = 0; ks < 2; ks++) {
            bf16x8 af[4], bfr[4];
            const int ck = ks * 4 + lq;
            #pragma unroll
            for (int f = 0; f < 4; f++) {
                int ra = wi + f * 16 + lr;
                af[f]  = *(const bf16x8*)&Alds[ck * 1024 + ra * 8];
                int rb = wj + f * 16 + lr;
                bfr[f] = *(const bf16x8*)&Blds[ck * 1024 + rb * 8];
            }
            #pragma unroll
            for (int fi = 0; fi < 4; fi++)
                #pragma unroll
                for (int fj = 0; fj < 4; fj++)
                    acc[fi][fj] = __builtin_amdgcn_mfma_f32_16x16x32_bf16(
                        af[fi], bfr[fj], acc[fi][fj], 0, 0, 0);
        }
    }

    // ---- epilogue: BN (scale/shift) + optional ReLU
    if constexpr (NHWC_OUT) {
        int jc[4];
        #pragma unroll
        for (int fj = 0; fj < 4; fj++) jc[fj] = jt * 128 + wj + fj * 16 + lr;
        #pragma unroll
        for (int fi = 0; fi < 4; fi++) {
            int rb = it * 128 + wi + fi * 16 + lq * 4;
            f32x4 sc = *(const f32x4*)&scale[rb];
            f32x4 sh = *(const f32x4*)&shift[rb];
            #pragma unroll
            for (int fj = 0; fj < 4; fj++) {
                Pack4 pk;
                #pragma unroll
                for (int reg = 0; reg < 4; reg++) {
                    float v = acc[fi][fj][reg] * sc[reg] + sh[reg];
                    if (RELU) v = fmaxf(v, 0.f);
                    pk.u[reg] = f2bf(v);
                }
                *(uint2*)&((u16*)out)[(size_t)jc[fj] * 256 + rb] = pk.v2;
            }
        }
    } else {
        int jcb[4], jcm[4];
        #pragma unroll
        for (int fj = 0; fj < 4; fj++) {
            int jc = jt * 128 + wj + fj * 16 + lr;
            int b = jc / HoWo;
            jcb[fj] = b; jcm[fj] = jc - b * HoWo;
        }
        #pragma unroll
        for (int fi = 0; fi < 4; fi++) {
            int rb = it * 128 + wi + fi * 16 + lq * 4;
            f32x4 sc = *(const f32x4*)&scale[rb];
            f32x4 sh = *(const f32x4*)&shift[rb];
            #pragma unroll
            for (int reg = 0; reg < 4; reg++) {
                int r = rb + reg;
                #pragma unroll
                for (int fj = 0; fj < 4; fj++) {
                    float v = acc[fi][fj][reg] * sc[reg] + sh[reg];
                    if (RELU) v = fmaxf(v, 0.f);
                    size_t o = ((size_t)(jcb[fj] * 256 + r)) * HoWo + jcm[fj];
                    ((float*)out)[o] = v;
                }
            }
        }
    }
}

// ---------------------------------------------------------------------------
// Depthwise xcorr, NHWC: feat[b,oy,ox,c] = sum_{5x5} s[b,oy+dy,ox+dx,c]*k[b,dy,dx,c]
// grid (b*25), thread = channel; rows register-resident.
// ---------------------------------------------------------------------------
__global__ __launch_bounds__(256)
void xcorr_kernel(const u16* __restrict__ s, const u16* __restrict__ k,
                  u16* __restrict__ out)
{
    const int b = blockIdx.x / 25;
    const int oy = blockIdx.x - b * 25;
    const int c = threadIdx.x;

    float kf[25];
    #pragma unroll
    for (int t = 0; t < 25; t++)
        kf[t] = bf2f(k[((size_t)(b * 25 + t)) * 256 + c]);

    float acc[25];
    #pragma unroll
    for (int i = 0; i < 25; i++) acc[i] = 0.f;

    for (int dy = 0; dy < 5; dy++) {
        float row[29];
        const u16* sp = s + ((size_t)(b * 29 + oy + dy) * 29) * 256 + c;
        #pragma unroll
        for (int x = 0; x < 29; x++) row[x] = bf2f(sp[(size_t)x * 256]);
        #pragma unroll
        for (int dx = 0; dx < 5; dx++) {
            float kv = kf[dy * 5 + dx];
            #pragma unroll
            for (int ox = 0; ox < 25; ox++)
                acc[ox] += row[ox + dx] * kv;
        }
    }
    u16* op = out + ((size_t)(b * 25 + oy) * 25) * 256 + c;
    #pragma unroll
    for (int ox = 0; ox < 25; ox++)
        op[(size_t)ox * 256] = f2bf(acc[ox]);
}

// ---------------------------------------------------------------------------
// Merged weight/BN prep (one launch)
// blocks [0,2304): wk->Wk2   [2304,4608): ws->Ws2
// blocks [4608,4864): wh1    [4864,5120): wh2     block 5120: BN fold
// ---------------------------------------------------------------------------
__global__ __launch_bounds__(256)
void prep_all(const float* __restrict__ wk, const float* __restrict__ wsw,
              const float* __restrict__ wh1, const float* __restrict__ wh2,
              const float* gk, const float* bk, const float* mk, const float* vk,
              const float* gs, const float* bs, const float* ms, const float* vs,
              const float* gh, const float* bh, const float* mh, const float* vh,
              const float* bh2,
              u16* __restrict__ Wk2, u16* __restrict__ Ws2,
              u16* __restrict__ Wh1b, u16* __restrict__ Wh2b,
              float* sk, float* tk, float* ss, float* ts,
              float* sh, float* th, float* s5, float* t5)
{
    int blk = blockIdx.x;
    int tidx = threadIdx.x;
    if (blk < 4608) {
        const float* w = (blk < 2304) ? wk : wsw;
        u16* o = (blk < 2304) ? Wk2 : Ws2;
        int idx = (blk % 2304) * 256 + tidx;
        int oc = idx / 2304, rem = idx - oc * 2304;
        int tap = rem >> 8, c = rem & 255;
        o[idx] = f2bf(w[oc * 2304 + c * 9 + tap]);
    } else if (blk < 5120) {
        const float* w = (blk < 4864) ? wh1 : wh2;
        u16* o = (blk < 4864) ? Wh1b : Wh2b;
        int idx = ((blk - 4608) % 256) * 256 + tidx;
        o[idx] = f2bf(w[idx]);
    } else {
        int i = tidx;
        float iv;
        iv = rsqrtf(vk[i] + EPS_BN) * gk[i]; sk[i] = iv; tk[i] = bk[i] - mk[i] * iv;
        iv = rsqrtf(vs[i] + EPS_BN) * gs[i]; ss[i] = iv; ts[i] = bs[i] - ms[i] * iv;
        iv = rsqrtf(vh[i] + EPS_BN) * gh[i]; sh[i] = iv; th[i] = bh[i] - mh[i] * iv;
        s5[i] = 1.f; t5[i] = bh2[i];
    }
}

// ---------------------------------------------------------------------------
extern "C" void kernel_launch(void* const* d_in, const int* in_sizes, int n_in,
                              void* d_out, int out_size, void* d_ws, size_t ws_size,
                              hipStream_t stream)
{
    const float* in_kernel = (const float*)d_in[0];
    const float* in_search = (const float*)d_in[1];
    const float* wk  = (const float*)d_in[2];
    const float* gk  = (const float*)d_in[3];
    const float* bk  = (const float*)d_in[4];
    const float* mk  = (const float*)d_in[5];
    const float* vk  = (const float*)d_in[6];
    const float* wsw = (const float*)d_in[7];
    const float* gs  = (const float*)d_in[8];
    const float* bs  = (const float*)d_in[9];
    const float* ms  = (const float*)d_in[10];
    const float* vs  = (const float*)d_in[11];
    const float* wh1 = (const float*)d_in[12];
    const float* gh  = (const float*)d_in[13];
    const float* bh  = (const float*)d_in[14];
    const float* mh  = (const float*)d_in[15];
    const float* vh  = (const float*)d_in[16];
    const float* wh2 = (const float*)d_in[17];
    const float* bh2 = (const float*)d_in[18];
    float* out = (float*)d_out;

    char* w = (char*)d_ws;
    u16* Wk2 = (u16*)w;  w += 1179648;      // 256*2304 bf16
    u16* Ws2 = (u16*)w;  w += 1179648;
    u16* Wh1 = (u16*)w;  w += 131072;       // 256*256 bf16
    u16* Wh2 = (u16*)w;  w += 131072;
    float* sk = (float*)w; w += 1024;
    float* tk = (float*)w; w += 1024;
    float* ss = (float*)w; w += 1024;
    float* ts = (float*)w; w += 1024;
    float* sh = (float*)w; w += 1024;
    float* th = (float*)w; w += 1024;
    float* s5 = (float*)w; w += 1024;
    float* t5 = (float*)w; w += 1024;
    u16* kfeat = (u16*)w; w += 1638400;     // 128*25*256 bf16
    u16* sfeat = (u16*)w; w += 55115776;    // 128*841*256 bf16
    u16* feat  = (u16*)w; w += 40960000;    // 128*625*256 bf16
    u16* ktr   = (u16*)w; w += 3211264;     // 128*49*256 bf16 (NHWC kernel input)
    u16* strA  = (u16*)w; w += 62980096;    // 128*961*256 bf16 (NHWC search input)
    u16* hbuf  = strA;                      // alias: strA dead after stage 2

    tr_all<<<481 + 25, 256, 0, stream>>>(in_search, in_kernel, strA, ktr);
    prep_all<<<5121, 256, 0, stream>>>(wk, wsw, wh1, wh2,
                                       gk, bk, mk, vk, gs, bs, ms, vs,
                                       gh, bh, mh, vh, bh2,
                                       Wk2, Ws2, Wh1, Wh2,
                                       sk, tk, ss, ts, sh, th, s5, t5);

    // stage 1: kernel tower  -> kfeat NHWC [128*25, 256]
    conv_gemm<9, true, u16, true><<<dim3(2, 25), 256, 0, stream>>>(
        ktr, Wk2, sk, tk, kfeat, 7, 7, 5, 5);
    // stage 2: search tower  -> sfeat NHWC [128*841, 256]
    conv_gemm<9, true, u16, true><<<dim3(2, 841), 256, 0, stream>>>(
        strA, Ws2, ss, ts, sfeat, 31, 31, 29, 29);
    // stage 3: depthwise xcorr -> feat NHWC [128*625, 256]
    xcorr_kernel<<<128 * 25, 256, 0, stream>>>(sfeat, kfeat, feat);
    // stage 4: head 1x1 + BN + ReLU -> hbuf NHWC
    conv_gemm<1, true, u16, true><<<dim3(2, 625), 256, 0, stream>>>(
        feat, Wh1, sh, th, hbuf, 25, 25, 25, 25);
    // stage 5: head 1x1 + bias -> out NCHW fp32
    conv_gemm<1, false, float, false><<<dim3(2, 625), 256, 0, stream>>>(
        hbuf, Wh2, s5, t5, out, 25, 25, 25, 25);

    (void)in_sizes; (void)n_in; (void)out_size; (void)ws_size;
}

// Round 4
// 702.683 us; speedup vs baseline: 1.3281x; 1.3281x over previous
//
#include <hip/hip_runtime.h>
#include <hip/hip_bf16.h>
#include <cstdint>
#include <cstddef>

typedef unsigned short u16;
typedef __attribute__((ext_vector_type(8))) __bf16 bf16x8;
typedef __attribute__((ext_vector_type(4))) float f32x4;

#define EPS_BN 1e-5f

__device__ __forceinline__ u16 f2bf(float f) {
    union { float f; uint32_t u; } v; v.f = f;
    uint32_t u = v.u;
    u += 0x7FFFu + ((u >> 16) & 1u);   // round-to-nearest-even
    return (u16)(u >> 16);
}
__device__ __forceinline__ float bf2f(u16 s) {
    union { uint32_t u; float f; } v; v.u = ((uint32_t)s) << 16;
    return v.f;
}

union Pack8 { u16 u[8]; uint4 v4; };
union Pack4 { u16 u[4]; uint2 v2; };

// async global -> LDS, 16B per lane; LDS dest = wave-uniform base + lane*16
typedef __attribute__((address_space(1))) const unsigned char as1c;
typedef __attribute__((address_space(3))) unsigned char as3;
__device__ __forceinline__ void gld_lds16(const void* g, void* l) {
    __builtin_amdgcn_global_load_lds((as1c*)g, (as3*)l, 16, 0, 0);
}

// ---------------------------------------------------------------------------
// Transpose NCHW fp32 -> NHWC bf16 (search + kernel inputs in one launch)
// ---------------------------------------------------------------------------
__device__ __forceinline__ void tr_one(const float* __restrict__ in,
                                       u16* __restrict__ out, int P, int p)
{
    int b = p / P, pp = p - b * P;
    const float* ip = in + (size_t)b * 256 * P + pp;
    u16* op = out + (size_t)p * 256;
    #pragma unroll 4
    for (int cg = 0; cg < 32; cg++) {
        Pack8 pk;
        #pragma unroll
        for (int i = 0; i < 8; i++)
            pk.u[i] = f2bf(ip[(size_t)(cg * 8 + i) * P]);
        *(uint4*)(op + cg * 8) = pk.v4;
    }
}

__global__ __launch_bounds__(256)
void tr_all(const float* __restrict__ s, const float* __restrict__ k,
            u16* __restrict__ so, u16* __restrict__ ko)
{
    int blk = blockIdx.x;
    if (blk < 481) {
        int p = blk * 256 + threadIdx.x;
        if (p < 128 * 961) tr_one(s, so, 961, p);
    } else {
        int p = (blk - 481) * 256 + threadIdx.x;
        if (p < 128 * 49) tr_one(k, ko, 49, p);
    }
}

// ---------------------------------------------------------------------------
// Implicit-im2col GEMM, NHWC bf16 input:
//   out[oc, (b,oy,ox)] = sum_k W[oc,k] * X[(b,oy,ox), k],  k = (tap, c)
// 128x128 tile, BK=64, 4 waves, 4x4 frags of 16x16x32 bf16 MFMA.
// Staging: global_load_lds width=16, flat g = q*256+tid, row=g>>3, chunk=g&7.
// Lane loads global chunk (c ^ (row&7)) -> LDS lands in XOR-swizzled
// [row][16B-chunk] layout (rows of 128B), conflict-free ds_read_b128,
// and each DMA instruction covers 8 aligned 128B global segments (coalesced).
// ---------------------------------------------------------------------------
template<int TAPS, bool NHWC_OUT, typename OutT, bool RELU>
__global__ __launch_bounds__(256)
void conv_gemm(const u16* __restrict__ in, const u16* __restrict__ W,
               const float* __restrict__ scale, const float* __restrict__ shift,
               OutT* __restrict__ out, int Hi, int Wi, int Ho, int Wo)
{
    constexpr int KT = TAPS * 256;
    constexpr int KB = KT / 64;
    const int HoWo = Ho * Wo;

    __shared__ u16 Alds[8192];   // 16 KB: [row 0..127][128B swizzled]
    __shared__ u16 Blds[8192];   // 16 KB: [pix 0..127][128B swizzled]

    const int tid = threadIdx.x;
    const int it = blockIdx.x;   // I tile (oc): 0..1
    const int jt = blockIdx.y;   // J tile
    const int wv = tid >> 6;
    const int lane = tid & 63;

    // ---- staging coords: chunk c8, row sub-index t3; row(q) = q*32 + t3
    const int c8 = tid & 7;
    const int t3 = tid >> 3;
    const int csw = c8 ^ (t3 & 7);     // swizzled global chunk (row&7 == t3&7)

    const u16* gA[4];
    const u16* gB[4];
    #pragma unroll
    for (int q = 0; q < 4; q++) {
        int r = q * 32 + t3;
        gA[q] = W + (size_t)(it * 128 + r) * KT + csw * 8;
        int jg = jt * 128 + r;
        int bb = jg / HoWo;
        int msp = jg - bb * HoWo;
        int oyp = msp / Wo;
        int oxp = msp - oyp * Wo;
        gB[q] = in + ((size_t)(bb * Hi + oyp) * Wi + oxp) * 256 + csw * 8;
    }

    // ---- MFMA coords
    const int wi = (wv >> 1) * 64;
    const int wj = (wv & 1) * 64;
    const int lr = lane & 15;
    const int lq = lane >> 4;

    f32x4 acc[4][4];
    #pragma unroll
    for (int a = 0; a < 4; a++)
        #pragma unroll
        for (int b = 0; b < 4; b++)
            acc[a][b] = (f32x4){0.f, 0.f, 0.f, 0.f};

    for (int kb = 0; kb < KB; kb++) {
        const int tap = (TAPS == 1) ? 0 : (kb >> 2);
        const int c0  = (TAPS == 1) ? (kb * 64) : ((kb & 3) * 64);
        int ky = 0, kx = 0;
        if (TAPS == 9) { ky = tap / 3; kx = tap - ky * 3; }
        const int aoff = tap * 256 + c0;
        const int boff = (ky * Wi + kx) * 256 + c0;
        __syncthreads();
        #pragma unroll
        for (int q = 0; q < 4; q++)
            gld_lds16(gA[q] + aoff, Alds + q * 2048 + wv * 512);
        #pragma unroll
        for (int q = 0; q < 4; q++)
            gld_lds16(gB[q] + boff, Blds + q * 2048 + wv * 512);
        __syncthreads();
        // ---- MFMA: 2 k-steps of 32
        #pragma unroll
        for (int ks = 0; ks < 2; ks++) {
            bf16x8 af[4], bfr[4];
            const int ck = ks * 4 + lq;
            #pragma unroll
            for (int f = 0; f < 4; f++) {
                int ra = wi + f * 16 + lr;
                af[f]  = *(const bf16x8*)&Alds[ra * 64 + ((ck ^ (ra & 7)) * 8)];
                int rb = wj + f * 16 + lr;
                bfr[f] = *(const bf16x8*)&Blds[rb * 64 + ((ck ^ (rb & 7)) * 8)];
            }
            #pragma unroll
            for (int fi = 0; fi < 4; fi++)
                #pragma unroll
                for (int fj = 0; fj < 4; fj++)
                    acc[fi][fj] = __builtin_amdgcn_mfma_f32_16x16x32_bf16(
                        af[fi], bfr[fj], acc[fi][fj], 0, 0, 0);
        }
    }

    // ---- epilogue: BN (scale/shift) + optional ReLU
    if constexpr (NHWC_OUT) {
        int jc[4];
        #pragma unroll
        for (int fj = 0; fj < 4; fj++) jc[fj] = jt * 128 + wj + fj * 16 + lr;
        #pragma unroll
        for (int fi = 0; fi < 4; fi++) {
            int rb = it * 128 + wi + fi * 16 + lq * 4;
            f32x4 sc = *(const f32x4*)&scale[rb];
            f32x4 sh = *(const f32x4*)&shift[rb];
            #pragma unroll
            for (int fj = 0; fj < 4; fj++) {
                Pack4 pk;
                #pragma unroll
                for (int reg = 0; reg < 4; reg++) {
                    float v = acc[fi][fj][reg] * sc[reg] + sh[reg];
                    if (RELU) v = fmaxf(v, 0.f);
                    pk.u[reg] = f2bf(v);
                }
                *(uint2*)&((u16*)out)[(size_t)jc[fj] * 256 + rb] = pk.v2;
            }
        }
    } else {
        int jcb[4], jcm[4];
        #pragma unroll
        for (int fj = 0; fj < 4; fj++) {
            int jc = jt * 128 + wj + fj * 16 + lr;
            int b = jc / HoWo;
            jcb[fj] = b; jcm[fj] = jc - b * HoWo;
        }
        #pragma unroll
        for (int fi = 0; fi < 4; fi++) {
            int rb = it * 128 + wi + fi * 16 + lq * 4;
            f32x4 sc = *(const f32x4*)&scale[rb];
            f32x4 sh = *(const f32x4*)&shift[rb];
            #pragma unroll
            for (int reg = 0; reg < 4; reg++) {
                int r = rb + reg;
                #pragma unroll
                for (int fj = 0; fj < 4; fj++) {
                    float v = acc[fi][fj][reg] * sc[reg] + sh[reg];
                    if (RELU) v = fmaxf(v, 0.f);
                    size_t o = ((size_t)(jcb[fj] * 256 + r)) * HoWo + jcm[fj];
                    ((float*)out)[o] = v;
                }
            }
        }
    }
}

// ---------------------------------------------------------------------------
// Depthwise xcorr, NHWC: feat[b,oy,ox,c] = sum_{5x5} s[b,oy+dy,ox+dx,c]*k[b,dy,dx,c]
// grid (b*25), thread = channel; rows register-resident.
// ---------------------------------------------------------------------------
__global__ __launch_bounds__(256)
void xcorr_kernel(const u16* __restrict__ s, const u16* __restrict__ k,
                  u16* __restrict__ out)
{
    const int b = blockIdx.x / 25;
    const int oy = blockIdx.x - b * 25;
    const int c = threadIdx.x;

    float kf[25];
    #pragma unroll
    for (int t = 0; t < 25; t++)
        kf[t] = bf2f(k[((size_t)(b * 25 + t)) * 256 + c]);

    float acc[25];
    #pragma unroll
    for (int i = 0; i < 25; i++) acc[i] = 0.f;

    for (int dy = 0; dy < 5; dy++) {
        float row[29];
        const u16* sp = s + ((size_t)(b * 29 + oy + dy) * 29) * 256 + c;
        #pragma unroll
        for (int x = 0; x < 29; x++) row[x] = bf2f(sp[(size_t)x * 256]);
        #pragma unroll
        for (int dx = 0; dx < 5; dx++) {
            float kv = kf[dy * 5 + dx];
            #pragma unroll
            for (int ox = 0; ox < 25; ox++)
                acc[ox] += row[ox + dx] * kv;
        }
    }
    u16* op = out + ((size_t)(b * 25 + oy) * 25) * 256 + c;
    #pragma unroll
    for (int ox = 0; ox < 25; ox++)
        op[(size_t)ox * 256] = f2bf(acc[ox]);
}

// ---------------------------------------------------------------------------
// Merged weight/BN prep (one launch)
// ---------------------------------------------------------------------------
__global__ __launch_bounds__(256)
void prep_all(const float* __restrict__ wk, const float* __restrict__ wsw,
              const float* __restrict__ wh1, const float* __restrict__ wh2,
              const float* gk, const float* bk, const float* mk, const float* vk,
              const float* gs, const float* bs, const float* ms, const float* vs,
              const float* gh, const float* bh, const float* mh, const float* vh,
              const float* bh2,
              u16* __restrict__ Wk2, u16* __restrict__ Ws2,
              u16* __restrict__ Wh1b, u16* __restrict__ Wh2b,
              float* sk, float* tk, float* ss, float* ts,
              float* sh, float* th, float* s5, float* t5)
{
    int blk = blockIdx.x;
    int tidx = threadIdx.x;
    if (blk < 4608) {
        const float* w = (blk < 2304) ? wk : wsw;
        u16* o = (blk < 2304) ? Wk2 : Ws2;
        int idx = (blk % 2304) * 256 + tidx;
        int oc = idx / 2304, rem = idx - oc * 2304;
        int tap = rem >> 8, c = rem & 255;
        o[idx] = f2bf(w[oc * 2304 + c * 9 + tap]);
    } else if (blk < 5120) {
        const float* w = (blk < 4864) ? wh1 : wh2;
        u16* o = (blk < 4864) ? Wh1b : Wh2b;
        int idx = ((blk - 4608) % 256) * 256 + tidx;
        o[idx] = f2bf(w[idx]);
    } else {
        int i = tidx;
        float iv;
        iv = rsqrtf(vk[i] + EPS_BN) * gk[i]; sk[i] = iv; tk[i] = bk[i] - mk[i] * iv;
        iv = rsqrtf(vs[i] + EPS_BN) * gs[i]; ss[i] = iv; ts[i] = bs[i] - ms[i] * iv;
        iv = rsqrtf(vh[i] + EPS_BN) * gh[i]; sh[i] = iv; th[i] = bh[i] - mh[i] * iv;
        s5[i] = 1.f; t5[i] = bh2[i];
    }
}

// ---------------------------------------------------------------------------
extern "C" void kernel_launch(void* const* d_in, const int* in_sizes, int n_in,
                              void* d_out, int out_size, void* d_ws, size_t ws_size,
                              hipStream_t stream)
{
    const float* in_kernel = (const float*)d_in[0];
    const float* in_search = (const float*)d_in[1];
    const float* wk  = (const float*)d_in[2];
    const float* gk  = (const float*)d_in[3];
    const float* bk  = (const float*)d_in[4];
    const float* mk  = (const float*)d_in[5];
    const float* vk  = (const float*)d_in[6];
    const float* wsw = (const float*)d_in[7];
    const float* gs  = (const float*)d_in[8];
    const float* bs  = (const float*)d_in[9];
    const float* ms  = (const float*)d_in[10];
    const float* vs  = (const float*)d_in[11];
    const float* wh1 = (const float*)d_in[12];
    const float* gh  = (const float*)d_in[13];
    const float* bh  = (const float*)d_in[14];
    const float* mh  = (const float*)d_in[15];
    const float* vh  = (const float*)d_in[16];
    const float* wh2 = (const float*)d_in[17];
    const float* bh2 = (const float*)d_in[18];
    float* out = (float*)d_out;

    char* w = (char*)d_ws;
    u16* Wk2 = (u16*)w;  w += 1179648;      // 256*2304 bf16
    u16* Ws2 = (u16*)w;  w += 1179648;
    u16* Wh1 = (u16*)w;  w += 131072;       // 256*256 bf16
    u16* Wh2 = (u16*)w;  w += 131072;
    float* sk = (float*)w; w += 1024;
    float* tk = (float*)w; w += 1024;
    float* ss = (float*)w; w += 1024;
    float* ts = (float*)w; w += 1024;
    float* sh = (float*)w; w += 1024;
    float* th = (float*)w; w += 1024;
    float* s5 = (float*)w; w += 1024;
    float* t5 = (float*)w; w += 1024;
    u16* kfeat = (u16*)w; w += 1638400;     // 128*25*256 bf16
    u16* sfeat = (u16*)w; w += 55115776;    // 128*841*256 bf16
    u16* feat  = (u16*)w; w += 40960000;    // 128*625*256 bf16
    u16* ktr   = (u16*)w; w += 3211264;     // 128*49*256 bf16 (NHWC kernel input)
    u16* strA  = (u16*)w; w += 62980096;    // 128*961*256 bf16 (NHWC search input)
    u16* hbuf  = strA;                      // alias: strA dead after stage 2

    tr_all<<<481 + 25, 256, 0, stream>>>(in_search, in_kernel, strA, ktr);
    prep_all<<<5121, 256, 0, stream>>>(wk, wsw, wh1, wh2,
                                       gk, bk, mk, vk, gs, bs, ms, vs,
                                       gh, bh, mh, vh, bh2,
                                       Wk2, Ws2, Wh1, Wh2,
                                       sk, tk, ss, ts, sh, th, s5, t5);

    // stage 1: kernel tower  -> kfeat NHWC [128*25, 256]
    conv_gemm<9, true, u16, true><<<dim3(2, 25), 256, 0, stream>>>(
        ktr, Wk2, sk, tk, kfeat, 7, 7, 5, 5);
    // stage 2: search tower  -> sfeat NHWC [128*841, 256]
    conv_gemm<9, true, u16, true><<<dim3(2, 841), 256, 0, stream>>>(
        strA, Ws2, ss, ts, sfeat, 31, 31, 29, 29);
    // stage 3: depthwise xcorr -> feat NHWC [128*625, 256]
    xcorr_kernel<<<128 * 25, 256, 0, stream>>>(sfeat, kfeat, feat);
    // stage 4: head 1x1 + BN + ReLU -> hbuf NHWC
    conv_gemm<1, true, u16, true><<<dim3(2, 625), 256, 0, stream>>>(
        feat, Wh1, sh, th, hbuf, 25, 25, 25, 25);
    // stage 5: head 1x1 + bias -> out NCHW fp32
    conv_gemm<1, false, float, false><<<dim3(2, 625), 256, 0, stream>>>(
        hbuf, Wh2, s5, t5, out, 25, 25, 25, 25);

    (void)in_sizes; (void)n_in; (void)out_size; (void)ws_size;
}